// Round 14
// baseline (50.986 us; speedup 1.0000x reference)
//
#include <hip/hip_runtime.h>

#define W 512
#define H 512
#define OWID 506
#define OHT 506
#define BC 48              // 16 images * 3 channels
#define NSTRIP 3           // strips at cols 0 / 248 / 496 (16B-aligned)
#define SBASE 248
#define CH 14              // output rows per chunk (2 groups of 7)
#define NCHUNK 37          // 37*14 = 518 >= 506
#define NWAVE (BC*NSTRIP*NCHUNK)   // 5328, divisible by 4
#define NPIX 12289728.0f           // 16*3*506*506

__device__ __forceinline__ float clip01(float v) { return fminf(fmaxf(v, 0.f), 1.f); }

struct F4 { float a, b, c, d; };

__device__ __forceinline__ F4 ld4(const float* p) {
    const float4 v = *(const float4*)p;
    F4 r; r.a = v.x; r.b = v.y; r.c = v.z; r.d = v.w; return r;
}
__device__ __forceinline__ F4 clip4(F4 v) {
    F4 r; r.a = clip01(v.a); r.b = clip01(v.b); r.c = clip01(v.c); r.d = clip01(v.d);
    return r;
}
__device__ __forceinline__ F4 zmk(F4 x, F4 y) {    // x^2 + y^2 per col
    F4 r;
    r.a = fmaf(x.a, x.a, y.a * y.a);
    r.b = fmaf(x.b, x.b, y.b * y.b);
    r.c = fmaf(x.c, x.c, y.c * y.c);
    r.d = fmaf(x.d, x.d, y.d * y.d);
    return r;
}
__device__ __forceinline__ F4 xymk(F4 x, F4 y) {   // x*y per col
    F4 r; r.a = x.a * y.a; r.b = x.b * y.b; r.c = x.c * y.c; r.d = x.d * y.d;
    return r;
}
__device__ __forceinline__ void upd(F4& V, F4 n, F4 o) {
    V.a += n.a - o.a; V.b += n.b - o.b; V.c += n.c - o.c; V.d += n.d - o.d;
}
__device__ __forceinline__ void acc4(F4& V, F4 n) {
    V.a += n.a; V.b += n.b; V.c += n.c; V.d += n.d;
}

// 7-wide window sums for the lane's 4 contiguous cols; neighbors via shfl.
// cols: lane q owns {4q..4q+3}; S(4q+j) = sum V over cols [4q+j, 4q+j+6].
__device__ __forceinline__ F4 hsum4(F4 V) {
    float T  = V.a + V.b + V.c + V.d;
    float E  = T - V.d;              // a+b+c
    float G  = V.a + V.b;
    float U1 = __shfl_down(T, 1, 64);
    float E1 = __shfl_down(E, 1, 64);
    float F2 = __shfl_down(V.a, 2, 64);
    float G2 = __shfl_down(G, 2, 64);
    F4 S;
    S.a = T + E1;                    // own4 + next3
    S.b = (T - V.a) + U1;            // own3 + next4
    S.c = (V.c + V.d) + (U1 + F2);   // own2 + next4 + nextnext1
    S.d = V.d + (U1 + G2);           // own1 + next4 + nextnext2
    return S;
}

// sum-domain SSIM (scaled by 49^4)
__device__ __forceinline__ float ssim_v(float a0, float a1, float az, float a4) {
    const float c1p   = 0.2401f;        // C1 * 49^2
    const float c2p   = 2.1609f;        // C2 * 49^2
    const float covn  = 49.0f / 48.0f;
    const float covn2 = 49.0f / 24.0f;
    float t01  = a0 * a1;
    float qs   = fmaf(a0, a0, a1 * a1);
    float w4   = fmaf(49.f, a4, -t01);
    float num1 = fmaf(2.f, t01, c1p);
    float num2 = fmaf(covn2, w4, c2p);
    float w23  = fmaf(49.f, az, -qs);
    float den1 = qs + c1p;
    float den2 = fmaf(covn, w23, c2p);
    return (num1 * num2) * __builtin_amdgcn_rcpf(den1 * den2);
}

__global__ __launch_bounds__(256)
void ssim_stream(const float* __restrict__ pred, const float* __restrict__ targ,
                 float* __restrict__ partial, float* __restrict__ out_atomic)
{
    // wave-uniform id -> SGPR addressing, scalar row pointers
    const int wid  = __builtin_amdgcn_readfirstlane(blockIdx.x * 4 + (threadIdx.x >> 6));
    const int lane = threadIdx.x & 63;

    const int bc    = wid / (NSTRIP * NCHUNK);
    const int rem   = wid - bc * (NSTRIP * NCHUNK);
    const int strip = rem / NCHUNK;
    const int chunk = rem - strip * NCHUNK;

    const int base = strip * SBASE;          // 0 / 248 / 496 (scalar)
    const int lo   = (strip == 0) ? 0 : base + 2;   // dedupe vs prev strip (scalar)
    const int dc0  = 4 * lane;
    const int cb   = min(base + dc0, W - 4); // clamped, 16B-aligned float4 col

    bool okj[4];
    #pragma unroll
    for (int j = 0; j < 4; ++j) {
        int dc = dc0 + j, c = base + dc;
        okj[j] = (dc <= 249) && (c >= lo) && (c < OWID);
    }

    const int oy0 = chunk * CH;
    const size_t bb = (size_t)bc * (H * W) + (size_t)oy0 * W;
    const float* __restrict__ px = pred + bb;   // scalar base, row oy0
    const float* __restrict__ py = targ + bb;

    // ---- init rows 0..6 with one-row-ahead prefetch (rows <= 511) ----
    F4 ringx[7], ringy[7];
    F4 Vx = {0,0,0,0}, Vy = {0,0,0,0}, Vz = {0,0,0,0}, Vxy = {0,0,0,0};
    F4 nx = ld4(px + cb), ny = ld4(py + cb);           // row 0
    #pragma unroll
    for (int i = 0; i < 7; ++i) {
        F4 xr = nx, yr = ny;
        nx = ld4(px + (i + 1) * W + cb);               // rows 1..7 (<= 511)
        ny = ld4(py + (i + 1) * W + cb);
        F4 x = clip4(xr), y = clip4(yr);
        ringx[i] = x; ringy[i] = y;
        acc4(Vx, x); acc4(Vy, y);
        acc4(Vz, zmk(x, y)); acc4(Vxy, xymk(x, y));
    }
    // nx/ny hold row 7; scalar prefetch pointers for row 8+, clamped
    const int r8 = min(oy0 + 8, H - 1) - oy0;
    const float* fx = px + r8 * W;
    const float* fy = py + r8 * W;
    int rabs = oy0 + 8;

    float acc = 0.f;

    #pragma unroll 1
    for (int g = 0; g < 2; ++g) {
        if (oy0 + 7 * g >= OHT) break;     // scalar early-exit (last chunk)
        #pragma unroll
        for (int i = 0; i < 7; ++i) {      // t = 7g+i; ring slot i (compile-time)
            const int t = g * 7 + i;
            // ---- emit output row oy0+t: 4 cols/lane ----
            {
                F4 Sx = hsum4(Vx);
                F4 Sy = hsum4(Vy);
                F4 Sz = hsum4(Vz);
                F4 Sw = hsum4(Vxy);
                float v0 = ssim_v(Sx.a, Sy.a, Sz.a, Sw.a);
                float v1 = ssim_v(Sx.b, Sy.b, Sz.b, Sw.b);
                float v2 = ssim_v(Sx.c, Sy.c, Sz.c, Sw.c);
                float v3 = ssim_v(Sx.d, Sy.d, Sz.d, Sw.d);
                bool rok = (oy0 + t) < OHT;              // scalar
                acc += (okj[0] && rok) ? v0 : 0.f;
                acc += (okj[1] && rok) ? v1 : 0.f;
                acc += (okj[2] && rok) ? v2 : 0.f;
                acc += (okj[3] && rok) ? v3 : 0.f;
            }
            // ---- advance: consume prefetched row t+7, prefetch row t+8 ----
            {
                F4 xo = ringx[i], yo = ringy[i];
                F4 xn = clip4(nx), yn = clip4(ny);
                nx = ld4(fx + cb);
                ny = ld4(fy + cb);
                if (rabs < H - 1) { fx += W; fy += W; }  // scalar guard
                ++rabs;
                upd(Vx, xn, xo);
                upd(Vy, yn, yo);
                upd(Vz, zmk(xn, yn), zmk(xo, yo));
                upd(Vxy, xymk(xn, yn), xymk(xo, yo));
                ringx[i] = xn; ringy[i] = yn;
            }
        }
    }

    // ---- wave reduction, one partial per wave ----
    #pragma unroll
    for (int off = 32; off >= 1; off >>= 1)
        acc += __shfl_down(acc, off, 64);
    if (lane == 0) {
        if (partial) partial[wid] = acc;
        else atomicAdd(out_atomic, acc);
    }
}

__global__ __launch_bounds__(256)
void ssim_finish(const float* __restrict__ partial, float* __restrict__ out)
{
    __shared__ float red[4];
    float s = 0.f;
    for (int i = threadIdx.x; i < NWAVE; i += 256) s += partial[i];
    #pragma unroll
    for (int off = 32; off >= 1; off >>= 1)
        s += __shfl_down(s, off, 64);
    if ((threadIdx.x & 63) == 0) red[threadIdx.x >> 6] = s;
    __syncthreads();
    if (threadIdx.x == 0) {
        float t = red[0] + red[1] + red[2] + red[3];
        out[0] = 1.0f - t / NPIX;
    }
}

__global__ void ssim_zero(float* out) { out[0] = 0.0f; }
__global__ void ssim_finish_atomic(float* out) { out[0] = 1.0f - out[0] / NPIX; }

extern "C" void kernel_launch(void* const* d_in, const int* in_sizes, int n_in,
                              void* d_out, int out_size, void* d_ws, size_t ws_size,
                              hipStream_t stream) {
    const float* pred = (const float*)d_in[0];
    const float* targ = (const float*)d_in[1];
    float* out = (float*)d_out;

    dim3 block(256);
    dim3 grid(NWAVE / 4);   // 1332 blocks, 4 waves each

    if (ws_size >= (size_t)NWAVE * sizeof(float)) {
        float* part = (float*)d_ws;
        ssim_stream<<<grid, block, 0, stream>>>(pred, targ, part, nullptr);
        ssim_finish<<<1, 256, 0, stream>>>(part, out);
    } else {
        ssim_zero<<<1, 1, 0, stream>>>(out);
        ssim_stream<<<grid, block, 0, stream>>>(pred, targ, nullptr, out);
        ssim_finish_atomic<<<1, 1, 0, stream>>>(out);
    }
}